// Round 1
// 153.840 us; speedup vs baseline: 1.0174x; 1.0174x over previous
//
#include <hip/hip_runtime.h>

#define HID 20

typedef float v2f __attribute__((ext_vector_type(2)));

// Native-instruction SiLU on a packed pair. exp/rcp are scalar trans ops
// (quarter-rate); surrounding muls pack as v_pk_*. Formula kept bit-identical
// to the previous kernel (same constant, same op order per scalar lane).
__device__ __forceinline__ v2f silu2(v2f a) {
    v2f s = a * (-1.442695040888963f);        // one v_pk_mul_f32
    float e0 = __builtin_amdgcn_exp2f(s.x);   // exp(-a0)
    float e1 = __builtin_amdgcn_exp2f(s.y);   // exp(-a1)
    v2f rc;
    rc.x = __builtin_amdgcn_rcpf(1.0f + e0);
    rc.y = __builtin_amdgcn_rcpf(1.0f + e1);
    return a * rc;                            // one v_pk_mul_f32
}

// 20->20 layer on a pair of points, j-blocked by JB with i as the middle
// loop. Rationale (R4): the R1-R3 schedule collapsed to 44 VGPRs = 1-2 acc
// chains in flight -> VALU issue stalled on pk_fma latency (VALUBusy 52%).
// JB=4 forces 4 independent acc chains (dep distance 8cy) and ~96 live
// VGPRs, while weight rows stay contiguous (4 rows = 320B) so scalar loads
// still batch as s_load_dwordx16. Per-output summation order is unchanged
// (bias init, ascending i) -> bitwise-stable vs reference.
template <int JB>
__device__ __forceinline__ void layer20(const float* __restrict__ W,
                                        const float* __restrict__ b,
                                        const v2f* __restrict__ h,
                                        v2f* __restrict__ hn) {
    static_assert(HID % JB == 0, "JB must divide HID");
    #pragma unroll
    for (int jb = 0; jb < HID; jb += JB) {
        v2f acc[JB];
        #pragma unroll
        for (int j = 0; j < JB; ++j) {
            float bj = b[jb + j];
            acc[j] = (v2f){bj, bj};
        }
        #pragma unroll
        for (int i = 0; i < HID; ++i) {
            v2f hi = h[i];
            #pragma unroll
            for (int j = 0; j < JB; ++j) {
                float w = W[(jb + j) * HID + i];
                acc[j] = __builtin_elementwise_fma(hi, (v2f){w, w}, acc[j]);
            }
        }
        #pragma unroll
        for (int j = 0; j < JB; ++j)
            hn[jb + j] = silu2(acc[j]);
    }
}

// Live set target: h(40) + hn(<=36) + acc(8) + temps ~ 96-110 VGPR.
// (256,4): cap 128 VGPR -> 4-5 waves/SIMD; intra-wave ILP (4 chains) plus
// 4-5 resident waves should saturate the VALU issue port.
__global__ __launch_bounds__(256, 4) void SpringEquationNN_70102456205450_kernel(
    const float* __restrict__ t,
    const float* __restrict__ W0, const float* __restrict__ b0,
    const float* __restrict__ W1, const float* __restrict__ b1,
    const float* __restrict__ W2, const float* __restrict__ b2,
    const float* __restrict__ W3, const float* __restrict__ b3,
    const float* __restrict__ W4, const float* __restrict__ b4,
    const float* __restrict__ W5, const float* __restrict__ b5,
    const float* __restrict__ W6, const float* __restrict__ b6,
    const float* __restrict__ W7, const float* __restrict__ b7,
    float* __restrict__ out, int n)
{
    int idx = blockIdx.x * blockDim.x + threadIdx.x;   // pair index
    int p0 = 2 * idx;
    if (p0 >= n) return;

    // Coalesced 8B load of two consecutive points (N is even: 1048576).
    v2f x = *(const v2f*)(t + p0);

    v2f h[HID], hn[HID];

    // Layer 0: 1 -> 20 on both points
    #pragma unroll
    for (int j = 0; j < HID; ++j) {
        float w = W0[j], bb = b0[j];
        v2f a = __builtin_elementwise_fma(x, (v2f){w, w}, (v2f){bb, bb});
        h[j] = silu2(a);
    }

    // Layers 1..6: 20 -> 20, SiLU
    layer20<4>(W1, b1, h, hn);
    layer20<4>(W2, b2, hn, h);
    layer20<4>(W3, b3, h, hn);
    layer20<4>(W4, b4, hn, h);
    layer20<4>(W5, b5, h, hn);
    layer20<4>(W6, b6, hn, h);

    // Layer 7: 20 -> 1 (no activation). Single serial chain in ascending-i
    // order to preserve the exact reference summation order.
    float b7v = b7[0];
    v2f acc = {b7v, b7v};
    #pragma unroll
    for (int i = 0; i < HID; ++i) {
        float w = W7[i];
        acc = __builtin_elementwise_fma(h[i], (v2f){w, w}, acc);
    }

    // Coalesced 8B store.
    *(v2f*)(out + p0) = acc;
}

extern "C" void kernel_launch(void* const* d_in, const int* in_sizes, int n_in,
                              void* d_out, int out_size, void* d_ws, size_t ws_size,
                              hipStream_t stream) {
    const float* t  = (const float*)d_in[0];
    const float* W0 = (const float*)d_in[1];
    const float* b0 = (const float*)d_in[2];
    const float* W1 = (const float*)d_in[3];
    const float* b1 = (const float*)d_in[4];
    const float* W2 = (const float*)d_in[5];
    const float* b2 = (const float*)d_in[6];
    const float* W3 = (const float*)d_in[7];
    const float* b3 = (const float*)d_in[8];
    const float* W4 = (const float*)d_in[9];
    const float* b4 = (const float*)d_in[10];
    const float* W5 = (const float*)d_in[11];
    const float* b5 = (const float*)d_in[12];
    const float* W6 = (const float*)d_in[13];
    const float* b6 = (const float*)d_in[14];
    const float* W7 = (const float*)d_in[15];
    const float* b7 = (const float*)d_in[16];
    float* out = (float*)d_out;

    int n = in_sizes[0];             // N points
    int pairs = (n + 1) / 2;         // threads (N=1048576 -> 524288)
    int block = 256;
    int grid = (pairs + block - 1) / block;
    SpringEquationNN_70102456205450_kernel<<<grid, block, 0, stream>>>(
        t, W0, b0, W1, b1, W2, b2, W3, b3, W4, b4, W5, b5, W6, b6, W7, b7,
        out, n);
}